// Round 2
// baseline (121244.177 us; speedup 1.0000x reference)
//
#include <hip/hip_runtime.h>

typedef unsigned short u16;
typedef __attribute__((ext_vector_type(4))) float f32x4;
typedef __attribute__((ext_vector_type(8))) short short8;

#define NUM_T 256
#define BATCH 1024
#define DIM 64
#define HID 768
#define PHID 512
#define PREP 10
#define GIN 640            // DIM*PREP
#define COVSZ 32
#define COVH 128
#define DT_ 0.05f
#define VEPS 1e-6f
#define NTH 1024
#define NWAVE 16
#define NWG 64

// LDS row strides (elements); pads keep row stride != 0 mod 128B
#define LHF 772
#define LHB 776
#define LPH 520
#define LPF 132
#define LPB 136
#define LGI 648

struct Params {
  const float *X, *M; const int *obs; const float *cov;
  const float *bxz, *bxn, *bp1, *bp2, *bc1, *bc2, *bih, *bhh, *wprep, *bprep;
  const float *Wc1, *Wc2;
  const u16 *Wxz, *Wxn, *Whz, *Whn, *Wp1, *Wp2, *Wih, *Whh;
  float *out_h; float *partials;
};

__device__ __forceinline__ u16 f2bf(float f){
  unsigned u = __builtin_bit_cast(unsigned, f);
  u = (u + 0x7FFFu + ((u >> 16) & 1u)) >> 16;
  return (u16)u;
}
__device__ __forceinline__ float bf2f(u16 h){
  unsigned u = ((unsigned)h) << 16;
  return __builtin_bit_cast(float, u);
}
__device__ __forceinline__ float sigm(float x){ return 1.0f/(1.0f + __expf(-x)); }
__device__ __forceinline__ float tanh_f(float x){
  float t = __expf(-2.0f*fabsf(x));
  float r = (1.0f - t)/(1.0f + t);
  return x >= 0.0f ? r : -r;
}

struct Smem {
  float h_f[16*LHF];     // fp32 master h
  u16   h_b[16*LHB];     // bf16 copy (MFMA A operand)
  u16   ph1[16*LPH];
  float p_f[16*LPF];     // fp32 p for NLL
  u16   p_b[16*LPB];     // bf16 p for ODE GEMMs
  union U {
    struct ZN { u16 z_b[16*LHB]; u16 zh_b[16*LHB]; } zn;
    u16 gi_b[16*LGI];
  } u;
  int om[16];
  float red[NWAVE];
};

// Weights pre-swizzled fragment-major: W2[((t*NK + k)*64 + lane)*8 + e]
//   = W[t*16 + (lane&15)][k*32 + (lane>>4)*8 + e]
// One wave k-step load = contiguous 1KB (lane*16B). Depth-2 register pipeline.
template<int K, int NT, int TS>
__device__ __forceinline__ void dotT(const u16* __restrict__ A, int lda,
    const u16* __restrict__ W2, int t0, f32x4* acc, int c, int g, int lane)
{
  constexpr int NK = K/32;
  const u16* a = A + c*lda + g*8;
  const short8* wp[NT];
  #pragma unroll
  for (int j = 0; j < NT; ++j)
    wp[j] = (const short8*)(W2 + (((size_t)(t0 + TS*j)*NK)*64 + (size_t)lane)*8);
  short8 buf[2][NT];
  #pragma unroll
  for (int j = 0; j < NT; ++j) buf[0][j] = wp[j][0];
  #pragma unroll
  for (int j = 0; j < NT; ++j) buf[1][j] = wp[j][64];
  #pragma unroll
  for (int k = 0; k < NK; ++k){
    short8 av = *(const short8*)(a + 32*k);
    short8 cur[NT];
    #pragma unroll
    for (int j = 0; j < NT; ++j) cur[j] = buf[k & 1][j];
    if (k + 2 < NK){
      #pragma unroll
      for (int j = 0; j < NT; ++j) buf[k & 1][j] = wp[j][64*(k + 2)];
    }
    #pragma unroll
    for (int j = 0; j < NT; ++j)
      acc[j] = __builtin_amdgcn_mfma_f32_16x16x32_bf16(av, cur[j], acc[j], 0, 0, 0);
  }
}

__global__ __launch_bounds__(NTH, 4) void nnfo_main(Params pr)
{
  __shared__ Smem sm;
  const int tid  = threadIdx.x;
  const int lane = tid & 63;
  const int w    = tid >> 6;          // wave 0..15
  const int c = lane & 15;            // output col / A row
  const int g = lane >> 4;            // k-group; output rows g*4+i
  const int wg = blockIdx.x;
  const int row0 = wg * 16;

  float loss = 0.0f;

  // ---- prologue: h0 = tanh(relu(cov@Wc1^T + bc1)@Wc2^T + bc2) ----
  for (int it = tid; it < 16*COVH; it += NTH){
    int r = it >> 7, j = it & 127;
    float acc = pr.bc1[j];
    const float* cv = pr.cov + (size_t)(row0 + r)*COVSZ;
    const float* wv = pr.Wc1 + (size_t)j*COVSZ;
    for (int k = 0; k < COVSZ; ++k) acc += cv[k]*wv[k];
    sm.p_f[r*LPF + j] = fmaxf(acc, 0.0f);
  }
  __syncthreads();
  for (int it = tid; it < 16*HID; it += NTH){
    int r = it / HID, j = it - r*HID;
    float acc = pr.bc2[j];
    const float* wv = pr.Wc2 + (size_t)j*COVH;
    for (int k = 0; k < COVH; ++k) acc += sm.p_f[r*LPF + k]*wv[k];
    float h = tanh_f(acc);
    sm.h_f[r*LHF + j] = h;
    sm.h_b[r*LHB + j] = f2bf(h);
  }
  __syncthreads();

  // p_model part 1: ph1 = relu(h@Wp1^T + bp1)   (N=512, NT=2)
  auto pm1 = [&]() {
    f32x4 acc[2] = {};
    dotT<HID, 2, 16>(sm.h_b, LHB, pr.Wp1, w, acc, c, g, lane);
    #pragma unroll
    for (int j = 0; j < 2; ++j){
      int n = (w + 16*j)*16 + c;
      float b = pr.bp1[n];
      #pragma unroll
      for (int i = 0; i < 4; ++i)
        sm.ph1[(g*4 + i)*LPH + n] = f2bf(fmaxf(acc[j][i] + b, 0.0f));
    }
  };
  // p_model part 2 (N=128: waves 0..7 only)
  auto pm2_f32 = [&]() {
    if (w < 8){
      f32x4 acc[1] = {};
      dotT<PHID, 1, 16>(sm.ph1, LPH, pr.Wp2, w, acc, c, g, lane);
      int n = w*16 + c;
      float b = pr.bp2[n];
      #pragma unroll
      for (int i = 0; i < 4; ++i) sm.p_f[(g*4 + i)*LPF + n] = acc[0][i] + b;
    }
  };

  #pragma unroll 1
  for (int t = 0; t < NUM_T; ++t){
    if (tid < 16) sm.om[tid] = pr.obs[(size_t)t*BATCH + row0 + tid];

    // ---- stage 1: ph1 from current h ----
    pm1();
    __syncthreads();

    // ---- stage 2: ODE p -> bf16 ----
    if (w < 8){
      f32x4 acc[1] = {};
      dotT<PHID, 1, 16>(sm.ph1, LPH, pr.Wp2, w, acc, c, g, lane);
      int n = w*16 + c;
      float b = pr.bp2[n];
      #pragma unroll
      for (int i = 0; i < 4; ++i) sm.p_b[(g*4 + i)*LPB + n] = f2bf(acc[0][i] + b);
    }
    __syncthreads();

    // ---- stage 3: z = sigmoid(p@Wxz^T + bxz + h@Whz^T); keep p@Wxn partial in regs ----
    {
      f32x4 accz[3] = {}, accn[3] = {};
      dotT<128, 3, 16>(sm.p_b, LPB, pr.Wxz, w, accz, c, g, lane);
      dotT<HID, 3, 16>(sm.h_b, LHB, pr.Whz, w, accz, c, g, lane);
      dotT<128, 3, 16>(sm.p_b, LPB, pr.Wxn, w, accn, c, g, lane);
      #pragma unroll
      for (int j = 0; j < 3; ++j){
        int n = (w + 16*j)*16 + c;
        float b = pr.bxz[n];
        #pragma unroll
        for (int i = 0; i < 4; ++i){
          int r = g*4 + i;
          float z = sigm(accz[j][i] + b);
          float h = sm.h_f[r*LHF + n];
          sm.u.zn.z_b [r*LHB + n] = f2bf(z);
          sm.u.zn.zh_b[r*LHB + n] = f2bf(z*h);
        }
      }
      __syncthreads();

      // ---- stage 4: n = tanh(... + (z*h)@Whn^T); h += dt*(1-z)*(n-h) ----
      dotT<HID, 3, 16>(sm.u.zn.zh_b, LHB, pr.Whn, w, accn, c, g, lane);
      #pragma unroll
      for (int j = 0; j < 3; ++j){
        int n = (w + 16*j)*16 + c;
        float b = pr.bxn[n];
        #pragma unroll
        for (int i = 0; i < 4; ++i){
          int r = g*4 + i;
          float nv = tanh_f(accn[j][i] + b);
          float z  = bf2f(sm.u.zn.z_b[r*LHB + n]);
          float h  = sm.h_f[r*LHF + n];
          h = h + DT_*(1.0f - z)*(nv - h);
          sm.h_f[r*LHF + n] = h;
          sm.h_b[r*LHB + n] = f2bf(h);
        }
      }
    }
    __syncthreads();

    // ---- stages 5-6: p2 = p_model(h) -> fp32 ----
    pm1();
    __syncthreads();
    pm2_f32();
    __syncthreads();

    // ---- stage 7: nll_pre + build gi ----
    {
      int r = tid >> 6, d = tid & 63;   // 1024 threads == 16*64 exactly
      size_t xoff = ((size_t)t*BATCH + row0 + r)*DIM + d;
      float Xv = pr.X[xoff];
      float om = sm.om[r] ? 1.0f : 0.0f;
      float Mv = pr.M[xoff] * om;
      float mean = sm.p_f[r*LPF + d];
      float var  = sm.p_f[r*LPF + 64 + d];
      float av   = fabsf(var) + VEPS;
      float inv  = rsqrtf(av);
      float errv = (Xv - mean)*inv;
      loss += 0.5f*(errv*errv + __logf(av))*Mv;
      #pragma unroll
      for (int p = 0; p < PREP; ++p){
        float s = pr.bprep[d*PREP + p]
                + Xv  * pr.wprep[(d*4 + 0)*PREP + p]
                + mean* pr.wprep[(d*4 + 1)*PREP + p]
                + av  * pr.wprep[(d*4 + 2)*PREP + p]
                + errv* pr.wprep[(d*4 + 3)*PREP + p];
        sm.u.gi_b[r*LGI + d*PREP + p] = f2bf(fmaxf(s, 0.0f)*Mv);
      }
    }
    __syncthreads();

    // ---- stage 8: GRUCell jump ----
    {
      float hn_buf[3][4];
      #pragma unroll
      for (int j = 0; j < 3; ++j){
        int tt = w + 16*j;              // n-tile 0..47
        int n = tt*16 + c;
        f32x4 ai[3] = {};               // r,z,n gates from gi@Wih
        dotT<GIN, 3, 48>(sm.u.gi_b, LGI, pr.Wih, tt, ai, c, g, lane);
        f32x4 ah[3] = {};               // gates from h@Whh
        dotT<HID, 3, 48>(sm.h_b, LHB, pr.Whh, tt, ah, c, g, lane);
        #pragma unroll
        for (int i = 0; i < 4; ++i){
          int r = g*4 + i;
          float ir = ai[0][i] + pr.bih[n];
          float iz = ai[1][i] + pr.bih[HID + n];
          float in = ai[2][i] + pr.bih[2*HID + n];
          float hr = ah[0][i] + pr.bhh[n];
          float hz = ah[1][i] + pr.bhh[HID + n];
          float hn = ah[2][i] + pr.bhh[2*HID + n];
          float rr  = sigm(ir + hr);
          float zz  = sigm(iz + hz);
          float nn  = tanh_f(in + rr*hn);
          float ho  = sm.h_f[r*LHF + n];
          hn_buf[j][i] = (1.0f - zz)*nn + zz*ho;
        }
      }
      __syncthreads();   // all reads of h_b/h_f done before conditional overwrite
      #pragma unroll
      for (int j = 0; j < 3; ++j){
        int n = (w + 16*j)*16 + c;
        #pragma unroll
        for (int i = 0; i < 4; ++i){
          int r = g*4 + i;
          if (sm.om[r]){
            float v = hn_buf[j][i];
            sm.h_f[r*LHF + n] = v;
            sm.h_b[r*LHB + n] = f2bf(v);
          }
        }
      }
    }
    __syncthreads();

    // ---- stages 9-10: p3 = p_model(h) -> fp32 ----
    pm1();
    __syncthreads();
    pm2_f32();
    __syncthreads();

    // ---- stage 11: nll_post ----
    {
      int r = tid >> 6, d = tid & 63;
      size_t xoff = ((size_t)t*BATCH + row0 + r)*DIM + d;
      float Xv = pr.X[xoff];
      float om = sm.om[r] ? 1.0f : 0.0f;
      float Mv = pr.M[xoff] * om;
      float mean = sm.p_f[r*LPF + d];
      float var  = sm.p_f[r*LPF + 64 + d];
      float av   = fabsf(var) + VEPS;
      float inv  = rsqrtf(av);
      float errv = (Xv - mean)*inv;
      loss += 0.5f*(errv*errv + __logf(av))*Mv;   // MIXING = 1
    }
    __syncthreads();
  }

  // ---- write h rows (fp32) ----
  for (int it = tid; it < 16*HID; it += NTH){
    int r = it / HID, j = it - r*HID;
    pr.out_h[(size_t)(row0 + r)*HID + j] = sm.h_f[r*LHF + j];
  }
  // ---- loss reduce ----
  #pragma unroll
  for (int off = 32; off >= 1; off >>= 1) loss += __shfl_down(loss, off);
  if (lane == 0) sm.red[w] = loss;
  __syncthreads();
  if (tid == 0){
    float s = 0.0f;
    for (int i = 0; i < NWAVE; ++i) s += sm.red[i];
    pr.partials[wg] = s;
  }
}

// Convert + swizzle W (N x K, f32 row-major) -> fragment-major bf16:
// dst[((t*ks + k)*64 + lane)*8 + e] = W[t*16 + (lane&15)][k*32 + (lane>>4)*8 + e]
__global__ void k_swz(const float* __restrict__ s, u16* __restrict__ d, int N, int K){
  int i = blockIdx.x*blockDim.x + threadIdx.x;
  if (i >= N*K) return;
  int e    = i & 7;
  int lane = (i >> 3) & 63;
  int rest = i >> 9;             // t*ks + k
  int ks = K >> 5;
  int k = rest % ks, t = rest / ks;
  int c = lane & 15, g = lane >> 4;
  d[i] = f2bf(s[(size_t)(t*16 + c)*K + (k*32 + g*8 + e)]);
}

__global__ void k_final(const float* __restrict__ partials, float* __restrict__ out_loss){
  float v = partials[threadIdx.x];
  #pragma unroll
  for (int off = 32; off >= 1; off >>= 1) v += __shfl_down(v, off);
  if (threadIdx.x == 0) out_loss[0] = v;
}

extern "C" void kernel_launch(void* const* d_in, const int* in_sizes, int n_in,
                              void* d_out, int out_size, void* d_ws, size_t ws_size,
                              hipStream_t stream)
{
  const float* X   = (const float*)d_in[0];
  const float* M   = (const float*)d_in[1];
  const int*   obs = (const int*)  d_in[2];
  const float* cov = (const float*)d_in[3];
  const float* Wxz = (const float*)d_in[4];
  const float* bxz = (const float*)d_in[5];
  const float* Wxn = (const float*)d_in[6];
  const float* bxn = (const float*)d_in[7];
  const float* Whz = (const float*)d_in[8];
  const float* Whn = (const float*)d_in[9];
  const float* Wp1 = (const float*)d_in[10];
  const float* bp1 = (const float*)d_in[11];
  const float* Wp2 = (const float*)d_in[12];
  const float* bp2 = (const float*)d_in[13];
  const float* Wc1 = (const float*)d_in[14];
  const float* bc1 = (const float*)d_in[15];
  const float* Wc2 = (const float*)d_in[16];
  const float* bc2 = (const float*)d_in[17];
  const float* Wih = (const float*)d_in[18];
  const float* Whh = (const float*)d_in[19];
  const float* bih = (const float*)d_in[20];
  const float* bhh = (const float*)d_in[21];
  const float* wprep = (const float*)d_in[22];
  const float* bprep = (const float*)d_in[23];

  u16* w = (u16*)d_ws;
  u16* wXZ = w + 0;         // 768*128
  u16* wXN = w + 98304;     // 768*128
  u16* wHZ = w + 196608;    // 768*768
  u16* wHN = w + 786432;    // 768*768
  u16* wP1 = w + 1376256;   // 512*768
  u16* wP2 = w + 1769472;   // 128*512
  u16* wIH = w + 1835008;   // 2304*640
  u16* wHH = w + 3309568;   // 2304*768
  float* partials = (float*)((char*)d_ws + 10158080);

  struct CV { const float* s; u16* d; int N; int K; } cvs[8] = {
    {Wxz, wXZ, 768, 128}, {Wxn, wXN, 768, 128}, {Whz, wHZ, 768, 768}, {Whn, wHN, 768, 768},
    {Wp1, wP1, 512, 768}, {Wp2, wP2, 128, 512}, {Wih, wIH, 2304, 640}, {Whh, wHH, 2304, 768},
  };
  for (int i = 0; i < 8; ++i){
    int n = cvs[i].N * cvs[i].K;
    k_swz<<<(n + 255)/256, 256, 0, stream>>>(cvs[i].s, cvs[i].d, cvs[i].N, cvs[i].K);
  }

  Params pr { X, M, obs, cov, bxz, bxn, bp1, bp2, bc1, bc2, bih, bhh, wprep, bprep,
              Wc1, Wc2, wXZ, wXN, wHZ, wHN, wP1, wP2, wIH, wHH,
              (float*)d_out, partials };
  nnfo_main<<<NWG, NTH, 0, stream>>>(pr);
  k_final<<<1, 64, 0, stream>>>(partials, (float*)d_out + (size_t)BATCH*HID);
}